// Round 1
// baseline (147.981 us; speedup 1.0000x reference)
//
#include <hip/hip_runtime.h>
#include <hip/hip_fp16.h>

// DAS beamforming: out[b,z,x,k] = sum_c lerp(rf[b,c], delay(b,c,z,x))[k]
// Round 6: fp16 LDS residency.
//  Evidence: poison fill of ws (256 MiB, ~41 us) is timed and fixed; das < 41 us
//  and is dominated by the RANDOM LDS gather (g is uniform-random points, so
//  i0 is random -> ~8-way bank-group conflicts on 16-B float4 samples).
//  Fix: pre-convert rf to half4 (one kernel, 12 MB traffic). Gather becomes
//  ONE ds_read2_b64 (16 B, y0+y1 contiguous) per (px,ch) instead of two
//  ds_read_b128 (32 B): LDS bytes halve AND random addresses spread over
//  16 bank-groups instead of 8. Staging traffic halves (134 MB from L2).
//  Lerp stays f32 via v_fma_mix (fpext(half)*w+acc pattern).
//  Geometry kept from R5: 512 blocks = 2 batch x 32 tiles x 8 chunks, 1024 thr,
//  2 blocks/CU; partials in ws + reduce kernel (no contended atomics).

#define NBATCH 2
#define NC 128
#define NS 2048
#define NK 4
#define NM 65536                              // Nz*Nx pixels per batch

#define THREADS 1024
#define PX_PER_THREAD 2
#define PX_PER_BLOCK (THREADS * PX_PER_THREAD)   // 2048
#define C_PER_BLOCK 16
#define N_CHUNKS (NC / C_PER_BLOCK)           // 8
#define N_TILES (NM / PX_PER_BLOCK)           // 32
#define NBLOCKS (NBATCH * N_TILES * N_CHUNKS) // 512 = 2 blocks/CU, 32 waves/CU

#define PART_BYTES ((size_t)N_CHUNKS * NBATCH * NM * NK * 4)  // 16.8 MB
#define RF16_BYTES ((size_t)NBATCH * NC * NS * NK * 2)        // 4 MiB
#define N_SAMPLES (NBATCH * NC * NS)          // 524288 float4 samples

// ---------------- rf f32 -> fp16 pre-pass (runs every launch; ws is poisoned)
__global__ __launch_bounds__(256) void convert_kernel(
    const float4* __restrict__ rf, uint2* __restrict__ out)
{
    const int i = blockIdx.x * 256 + threadIdx.x;
    const float4 v = rf[i];
    const __half2 lo = __floats2half2_rn(v.x, v.y);
    const __half2 hi = __floats2half2_rn(v.z, v.w);
    out[i] = make_uint2(__builtin_bit_cast(unsigned, lo),
                        __builtin_bit_cast(unsigned, hi));
}

// Stage one fp16 channel slice (16 KiB) global->LDS async: 1 x 16 B per thread,
// lane-sequential LDS dest as the HW requires.
__device__ __forceinline__ void stage_channel16(const uint2* slice, uint2* lbuf, int t) {
    __builtin_amdgcn_global_load_lds(
        (const __attribute__((address_space(1))) void*)(slice + 2 * t),
        (__attribute__((address_space(3))) void*)(lbuf + 2 * t),
        16, 0, 0);
}

__global__ __launch_bounds__(THREADS, 8) void das16_kernel(
    const uint2* __restrict__ rf16, const float* __restrict__ g,
    const float* __restrict__ pr, const float* __restrict__ p,
    float* __restrict__ part)
{
    __shared__ uint2 sbuf[2][NS];   // 2 x 16 KiB double buffer (half4 samples)

    const int bid   = blockIdx.x;
    const int chunk = bid & (N_CHUNKS - 1);
    const int tile  = (bid >> 3) & (N_TILES - 1);
    const int b     = bid >> 8;
    const int t     = threadIdx.x;
    const int px0   = tile * PX_PER_BLOCK;

    const float c0v = p[b * 4 + 0];
    const float fsv = p[b * 4 + 1];
    const float t0v = p[b * 4 + 2];
    const float scale = fsv / c0v;            // samples per meter
    const float sb0   = scale * t0v;

    float gx[PX_PER_THREAD], gy[PX_PER_THREAD], gzv[PX_PER_THREAD], sbase[PX_PER_THREAD];
#pragma unroll
    for (int j = 0; j < PX_PER_THREAD; ++j) {
        const int m = px0 + j * THREADS + t;
        const float* gp = g + ((size_t)b * NM + m) * 3;
        gx[j]  = gp[0];
        gy[j]  = gp[1];
        gzv[j] = gp[2];
        sbase[j] = sb0 + scale * gzv[j];      // fs*(t0 + d_tx)/c0 hoisted
    }

    float4 acc[PX_PER_THREAD];
#pragma unroll
    for (int j = 0; j < PX_PER_THREAD; ++j) acc[j] = make_float4(0.f, 0.f, 0.f, 0.f);

    const int ch0 = chunk * C_PER_BLOCK;
    const uint2* slice0 = rf16 + (size_t)(b * NC + ch0) * NS;

    stage_channel16(slice0, &sbuf[0][0], t);

    for (int cc = 0; cc < C_PER_BLOCK; ++cc) {
        // vmcnt(0)+barrier: drains the stage into sbuf[cc&1] and protects
        // sbuf[(cc+1)&1] from overwrite while still being read. The co-resident
        // block computes through this stall.
        __syncthreads();
        if (cc + 1 < C_PER_BLOCK)
            stage_channel16(slice0 + (size_t)(cc + 1) * NS,
                            &sbuf[(cc + 1) & 1][0], t);  // in flight during compute

        const uint2* lb = &sbuf[cc & 1][0];
        const float* prp = pr + ((size_t)(b * NC + ch0 + cc)) * 3;
        const float prx = prp[0], pry = prp[1], prz = prp[2];

#pragma unroll
        for (int j = 0; j < PX_PER_THREAD; ++j) {
            const float dx = gx[j]  - prx;
            const float dy = gy[j]  - pry;
            const float dz = gzv[j] - prz;
            const float drx = __builtin_amdgcn_sqrtf(fmaf(dx, dx, fmaf(dy, dy, dz * dz)));
            float s = fmaf(scale, drx, sbase[j]);         // fractional sample index
            s = fminf(fmaxf(s, 0.0f), (float)(NS - 1));   // clamp
            const float fi = fminf(floorf(s), (float)(NS - 2));
            const float w  = s - fi;
            const float wm = 1.0f - w;
            const int i0 = (int)fi;
            const uint2 u0 = lb[i0];                      // y0 (half4) + y1 (half4):
            const uint2 u1 = lb[i0 + 1];                  // one ds_read2_b64 pair, 16 B
            const float2 y0a = __half22float2(__builtin_bit_cast(__half2, u0.x));
            const float2 y0b = __half22float2(__builtin_bit_cast(__half2, u0.y));
            const float2 y1a = __half22float2(__builtin_bit_cast(__half2, u1.x));
            const float2 y1b = __half22float2(__builtin_bit_cast(__half2, u1.y));
            acc[j].x = fmaf(y0a.x, wm, fmaf(y1a.x, w, acc[j].x));
            acc[j].y = fmaf(y0a.y, wm, fmaf(y1a.y, w, acc[j].y));
            acc[j].z = fmaf(y0b.x, wm, fmaf(y1b.x, w, acc[j].z));
            acc[j].w = fmaf(y0b.y, wm, fmaf(y1b.y, w, acc[j].w));
        }
    }

    // partial[chunk][b][m] as float4 — disjoint per block, plain stores
    float4* pw = (float4*)part + (size_t)(chunk * NBATCH + b) * NM;
#pragma unroll
    for (int j = 0; j < PX_PER_THREAD; ++j) {
        const int m = px0 + j * THREADS + t;
        pw[m] = acc[j];
    }
}

// ---------------- fallback (no usable ws): f32 staging + atomics to out
__device__ __forceinline__ void stage_channel32(const float* slice, float4* lbuf, int t) {
#pragma unroll
    for (int r = 0; r < (NS * NK / 4) / THREADS; ++r) {
        const int d = r * THREADS + t;
        __builtin_amdgcn_global_load_lds(
            (const __attribute__((address_space(1))) void*)(slice + (size_t)d * 4),
            (__attribute__((address_space(3))) void*)(lbuf + d),
            16, 0, 0);
    }
}

__global__ __launch_bounds__(THREADS, 8) void das32_atomic_kernel(
    const float* __restrict__ rf, const float* __restrict__ g,
    const float* __restrict__ pr, const float* __restrict__ p,
    float* __restrict__ out)
{
    __shared__ float4 sbuf[2][NS * NK / 4];

    const int bid   = blockIdx.x;
    const int chunk = bid & (N_CHUNKS - 1);
    const int tile  = (bid >> 3) & (N_TILES - 1);
    const int b     = bid >> 8;
    const int t     = threadIdx.x;
    const int px0   = tile * PX_PER_BLOCK;

    const float c0v = p[b * 4 + 0];
    const float fsv = p[b * 4 + 1];
    const float t0v = p[b * 4 + 2];
    const float scale = fsv / c0v;
    const float sb0   = scale * t0v;

    float gx[PX_PER_THREAD], gy[PX_PER_THREAD], gzv[PX_PER_THREAD], sbase[PX_PER_THREAD];
#pragma unroll
    for (int j = 0; j < PX_PER_THREAD; ++j) {
        const int m = px0 + j * THREADS + t;
        const float* gp = g + ((size_t)b * NM + m) * 3;
        gx[j]  = gp[0];
        gy[j]  = gp[1];
        gzv[j] = gp[2];
        sbase[j] = sb0 + scale * gzv[j];
    }

    float4 acc[PX_PER_THREAD];
#pragma unroll
    for (int j = 0; j < PX_PER_THREAD; ++j) acc[j] = make_float4(0.f, 0.f, 0.f, 0.f);

    const int ch0 = chunk * C_PER_BLOCK;
    const float* slice0 = rf + (size_t)(b * NC + ch0) * NS * NK;

    stage_channel32(slice0, &sbuf[0][0], t);

    for (int cc = 0; cc < C_PER_BLOCK; ++cc) {
        __syncthreads();
        if (cc + 1 < C_PER_BLOCK)
            stage_channel32(slice0 + (size_t)(cc + 1) * NS * NK,
                            &sbuf[(cc + 1) & 1][0], t);

        const float4* lb = &sbuf[cc & 1][0];
        const float* prp = pr + ((size_t)(b * NC + ch0 + cc)) * 3;
        const float prx = prp[0], pry = prp[1], prz = prp[2];

#pragma unroll
        for (int j = 0; j < PX_PER_THREAD; ++j) {
            const float dx = gx[j]  - prx;
            const float dy = gy[j]  - pry;
            const float dz = gzv[j] - prz;
            const float drx = __builtin_amdgcn_sqrtf(fmaf(dx, dx, fmaf(dy, dy, dz * dz)));
            float s = fmaf(scale, drx, sbase[j]);
            s = fminf(fmaxf(s, 0.0f), (float)(NS - 1));
            const float fi = fminf(floorf(s), (float)(NS - 2));
            const float w  = s - fi;
            const float wm = 1.0f - w;
            const int i0 = (int)fi;
            const float4 y0 = lb[i0];
            const float4 y1 = lb[i0 + 1];
            acc[j].x = fmaf(y0.x, wm, fmaf(y1.x, w, acc[j].x));
            acc[j].y = fmaf(y0.y, wm, fmaf(y1.y, w, acc[j].y));
            acc[j].z = fmaf(y0.z, wm, fmaf(y1.z, w, acc[j].z));
            acc[j].w = fmaf(y0.w, wm, fmaf(y1.w, w, acc[j].w));
        }
    }

    float* ob = out + (size_t)b * NM * NK;
#pragma unroll
    for (int j = 0; j < PX_PER_THREAD; ++j) {
        const int m = px0 + j * THREADS + t;
        float* op = ob + (size_t)m * NK;
        atomicAdd(op + 0, acc[j].x);
        atomicAdd(op + 1, acc[j].y);
        atomicAdd(op + 2, acc[j].z);
        atomicAdd(op + 3, acc[j].w);
    }
}

// out[i] = sum over 8 chunk partials; i indexes float4 over [B*NM)
__global__ __launch_bounds__(256) void reduce_kernel(
    const float4* __restrict__ part, float4* __restrict__ out)
{
    const int i = blockIdx.x * 256 + threadIdx.x;
    const size_t stride = (size_t)NBATCH * NM;
    float4 a = part[i];
#pragma unroll
    for (int c = 1; c < N_CHUNKS; ++c) {
        const float4 v = part[c * stride + i];
        a.x += v.x; a.y += v.y; a.z += v.z; a.w += v.w;
    }
    out[i] = a;
}

extern "C" void kernel_launch(void* const* d_in, const int* in_sizes, int n_in,
                              void* d_out, int out_size, void* d_ws, size_t ws_size,
                              hipStream_t stream) {
    (void)in_sizes; (void)n_in;
    const float* rf = (const float*)d_in[0];
    const float* g  = (const float*)d_in[1];
    const float* pr = (const float*)d_in[2];
    const float* p  = (const float*)d_in[3];
    float* out = (float*)d_out;

    if (ws_size >= PART_BYTES + RF16_BYTES) {
        uint2* rf16 = (uint2*)((char*)d_ws + PART_BYTES);
        convert_kernel<<<N_SAMPLES / 256, 256, 0, stream>>>((const float4*)rf, rf16);
        das16_kernel<<<NBLOCKS, THREADS, 0, stream>>>(rf16, g, pr, p, (float*)d_ws);
        reduce_kernel<<<(NBATCH * NM) / 256, 256, 0, stream>>>((const float4*)d_ws,
                                                               (float4*)out);
    } else {
        hipMemsetAsync(d_out, 0, (size_t)out_size * sizeof(float), stream);
        das32_atomic_kernel<<<NBLOCKS, THREADS, 0, stream>>>(rf, g, pr, p, out);
    }
}

// Round 2
// 130.468 us; speedup vs baseline: 1.1342x; 1.1342x over previous
//
#include <hip/hip_runtime.h>

// DAS beamforming: out[b,z,x,k] = sum_c lerp(rf[b,c], delay(b,c,z,x))[k]
// Round 7: revert R6's fp16-in-ws (HBM disaster: staging from the poisoned ws
// region forced 380 MB of HBM traffic/dispatch -> das 82 us). Back to R5's
// f32 staging from the CLEAN rf input (L2/LLC-resident), but with the staging
// volume halved structurally:
//   R5: PX_PER_THREAD=2, C_PER_BLOCK=16, N_TILES=32 -> rf staged 268 MB
//   R7: PX_PER_THREAD=4, C_PER_BLOCK=8,  N_TILES=16 -> rf staged 134 MB
// Grid stays 512 blocks = 2 blocks/CU (64 KiB LDS double-buffer each,
// 128 KiB/CU) so one block computes through the other's stage-drain barrier.
// Partials: 16 chunks (33.6 MB) + reduce kernel; plain stores only (R4 showed
// contended atomics are catastrophic).

#define NBATCH 2
#define NC 128
#define NS 2048
#define NK 4
#define NM 65536                              // Nz*Nx pixels per batch

#define THREADS 1024
#define PX_PER_THREAD 4
#define PX_PER_BLOCK (THREADS * PX_PER_THREAD)   // 4096
#define C_PER_BLOCK 8
#define N_CHUNKS (NC / C_PER_BLOCK)           // 16
#define N_TILES (NM / PX_PER_BLOCK)           // 16
#define NBLOCKS (NBATCH * N_TILES * N_CHUNKS) // 512 = 2 blocks/CU
#define SLICE_F4 (NS * NK / 4)                // 2048 float4 = 32 KiB / channel

#define PART_BYTES ((size_t)N_CHUNKS * NBATCH * NM * NK * 4)  // 33.6 MB

// Stage one channel slice (32 KiB) global->LDS async: 2 x 16 B per thread,
// lane-sequential LDS dest as the HW requires.
__device__ __forceinline__ void stage_channel(const float* slice, float4* lbuf, int t) {
#pragma unroll
    for (int r = 0; r < SLICE_F4 / THREADS; ++r) {
        const int d = r * THREADS + t;
        __builtin_amdgcn_global_load_lds(
            (const __attribute__((address_space(1))) void*)(slice + (size_t)d * 4),
            (__attribute__((address_space(3))) void*)(lbuf + d),
            16, 0, 0);
    }
}

template <bool ATOMIC>
__global__ __launch_bounds__(THREADS, 8) void das_kernel(
    const float* __restrict__ rf, const float* __restrict__ g,
    const float* __restrict__ pr, const float* __restrict__ p,
    float* __restrict__ dst)    // ATOMIC ? out : partials in ws
{
    __shared__ float4 sbuf[2][SLICE_F4];   // 2 x 32 KiB double buffer

    const int bid   = blockIdx.x;
    const int chunk = bid & (N_CHUNKS - 1);
    const int tile  = (bid >> 4) & (N_TILES - 1);
    const int b     = bid >> 8;
    const int t     = threadIdx.x;
    const int px0   = tile * PX_PER_BLOCK;

    const float c0v = p[b * 4 + 0];
    const float fsv = p[b * 4 + 1];
    const float t0v = p[b * 4 + 2];
    const float scale = fsv / c0v;            // samples per meter
    const float sb0   = scale * t0v;

    // keep persistent state lean (VGPR budget: 8 waves/EU -> <=64 VGPR):
    // gx,gy,gz (12) + acc (16) persistent; sample base folded per-iteration.
    float gx[PX_PER_THREAD], gy[PX_PER_THREAD], gzv[PX_PER_THREAD];
#pragma unroll
    for (int j = 0; j < PX_PER_THREAD; ++j) {
        const int m = px0 + j * THREADS + t;
        const float* gp = g + ((size_t)b * NM + m) * 3;
        gx[j]  = gp[0];
        gy[j]  = gp[1];
        gzv[j] = gp[2];
    }

    float4 acc[PX_PER_THREAD];
#pragma unroll
    for (int j = 0; j < PX_PER_THREAD; ++j) acc[j] = make_float4(0.f, 0.f, 0.f, 0.f);

    const int ch0 = chunk * C_PER_BLOCK;
    const float* slice0 = rf + (size_t)(b * NC + ch0) * NS * NK;

    stage_channel(slice0, &sbuf[0][0], t);

    for (int cc = 0; cc < C_PER_BLOCK; ++cc) {
        // vmcnt(0)+barrier: drains the stage into sbuf[cc&1] and protects
        // sbuf[(cc+1)&1] from overwrite while still being read. The co-resident
        // block computes through this stall.
        __syncthreads();
        if (cc + 1 < C_PER_BLOCK)
            stage_channel(slice0 + (size_t)(cc + 1) * NS * NK,
                          &sbuf[(cc + 1) & 1][0], t);  // in flight during compute

        const float4* lb = &sbuf[cc & 1][0];
        const float* prp = pr + ((size_t)(b * NC + ch0 + cc)) * 3;
        const float prx = prp[0], pry = prp[1], prz = prp[2];

#pragma unroll
        for (int j = 0; j < PX_PER_THREAD; ++j) {
            const float dx = gx[j]  - prx;
            const float dy = gy[j]  - pry;
            const float dz = gzv[j] - prz;
            const float drx = __builtin_amdgcn_sqrtf(fmaf(dx, dx, fmaf(dy, dy, dz * dz)));
            // s = fs*(t0 + gz + drx)/c0, folded: one add + one fma
            float s = fmaf(scale, gzv[j] + drx, sb0);
            s = fminf(fmaxf(s, 0.0f), (float)(NS - 1));   // clamp
            const float fi = fminf(floorf(s), (float)(NS - 2));
            const float w  = s - fi;
            const float wm = 1.0f - w;
            const int i0 = (int)fi;
            const float4 y0 = lb[i0];                     // adjacent 32 B:
            const float4 y1 = lb[i0 + 1];                 // 2x ds_read_b128
            acc[j].x = fmaf(y0.x, wm, fmaf(y1.x, w, acc[j].x));
            acc[j].y = fmaf(y0.y, wm, fmaf(y1.y, w, acc[j].y));
            acc[j].z = fmaf(y0.z, wm, fmaf(y1.z, w, acc[j].z));
            acc[j].w = fmaf(y0.w, wm, fmaf(y1.w, w, acc[j].w));
        }
    }

    if (ATOMIC) {
        float* ob = dst + (size_t)b * NM * NK;
#pragma unroll
        for (int j = 0; j < PX_PER_THREAD; ++j) {
            const int m = px0 + j * THREADS + t;
            float* op = ob + (size_t)m * NK;
            atomicAdd(op + 0, acc[j].x);
            atomicAdd(op + 1, acc[j].y);
            atomicAdd(op + 2, acc[j].z);
            atomicAdd(op + 3, acc[j].w);
        }
    } else {
        // partial[chunk][b][m] as float4 — disjoint per block, plain stores
        float4* pw = (float4*)dst + (size_t)(chunk * NBATCH + b) * NM;
#pragma unroll
        for (int j = 0; j < PX_PER_THREAD; ++j) {
            const int m = px0 + j * THREADS + t;
            pw[m] = acc[j];
        }
    }
}

// out[i] = sum over 16 chunk partials; i indexes float4 over [B*NM)
__global__ __launch_bounds__(256) void reduce_kernel(
    const float4* __restrict__ part, float4* __restrict__ out)
{
    const int i = blockIdx.x * 256 + threadIdx.x;
    const size_t stride = (size_t)NBATCH * NM;
    float4 a = part[i];
#pragma unroll
    for (int c = 1; c < N_CHUNKS; ++c) {
        const float4 v = part[c * stride + i];
        a.x += v.x; a.y += v.y; a.z += v.z; a.w += v.w;
    }
    out[i] = a;
}

extern "C" void kernel_launch(void* const* d_in, const int* in_sizes, int n_in,
                              void* d_out, int out_size, void* d_ws, size_t ws_size,
                              hipStream_t stream) {
    (void)in_sizes; (void)n_in;
    const float* rf = (const float*)d_in[0];
    const float* g  = (const float*)d_in[1];
    const float* pr = (const float*)d_in[2];
    const float* p  = (const float*)d_in[3];
    float* out = (float*)d_out;

    if (ws_size >= PART_BYTES) {
        das_kernel<false><<<NBLOCKS, THREADS, 0, stream>>>(rf, g, pr, p, (float*)d_ws);
        reduce_kernel<<<(NBATCH * NM) / 256, 256, 0, stream>>>((const float4*)d_ws,
                                                               (float4*)out);
    } else {
        hipMemsetAsync(d_out, 0, (size_t)out_size * sizeof(float), stream);
        das_kernel<true><<<NBLOCKS, THREADS, 0, stream>>>(rf, g, pr, p, out);
    }
}

// Round 4
// 92.098 us; speedup vs baseline: 1.6068x; 1.4166x over previous
//
#include <hip/hip_runtime.h>

// DAS beamforming: out[b,z,x,k] = sum_c lerp(rf[b,c], delay(b,c,z,x))[k]
// Round 9 = Round 8 with the compile fix: __builtin_nontemporal_* requires a
// native clang vector type, not HIP_vector_type. Theory unchanged:
//  R7 lesson: LLC is full of dirty poison lines after the 256 MiB ws fill;
//  every line das allocates evicts a dirty line -> HBM writeback billed to
//  das's window. R7's 33.6 MB of partial-store allocations also thrashed rf
//  out of the 4 MiB per-XCD L2 -> 83 MB rf re-fetch from HBM.
//  1. Partials are write-once/read-once: store them NON-TEMPORALLY (and read
//     them NT in reduce) so they never allocate in L2/LLC. rf stays
//     L2-resident; poison evictions shrink to das's own small footprint.
//  2. 8 chunks (C_PER_BLOCK=16) with PX_PER_THREAD=4: 256 blocks, staging
//     134 MB (L2-served), partials 16.8 MB.
//     chunk = bid&7 pins chunk<->XCD: per-XCD rf footprint = 1 MB << 4 MB L2.
//  Geometry: 256 blocks = 2 batch x 16 tiles x 8 chunks, 1024 thr, 1 block/CU
//  (64 KiB LDS double-buffer), 16 waves/CU.

#define NBATCH 2
#define NC 128
#define NS 2048
#define NK 4
#define NM 65536                              // Nz*Nx pixels per batch

#define THREADS 1024
#define PX_PER_THREAD 4
#define PX_PER_BLOCK (THREADS * PX_PER_THREAD)   // 4096
#define C_PER_BLOCK 16
#define N_CHUNKS (NC / C_PER_BLOCK)           // 8
#define N_TILES (NM / PX_PER_BLOCK)           // 16
#define NBLOCKS (NBATCH * N_TILES * N_CHUNKS) // 256 = 1 block/CU
#define SLICE_F4 (NS * NK / 4)                // 2048 float4 = 32 KiB / channel

#define PART_BYTES ((size_t)N_CHUNKS * NBATCH * NM * NK * 4)  // 16.8 MB

typedef float f32x4 __attribute__((ext_vector_type(4)));

// Stage one channel slice (32 KiB) global->LDS async: 2 x 16 B per thread,
// lane-sequential LDS dest as the HW requires.
__device__ __forceinline__ void stage_channel(const float* slice, float4* lbuf, int t) {
#pragma unroll
    for (int r = 0; r < SLICE_F4 / THREADS; ++r) {
        const int d = r * THREADS + t;
        __builtin_amdgcn_global_load_lds(
            (const __attribute__((address_space(1))) void*)(slice + (size_t)d * 4),
            (__attribute__((address_space(3))) void*)(lbuf + d),
            16, 0, 0);
    }
}

template <bool ATOMIC>
__global__ __launch_bounds__(THREADS, 8) void das_kernel(
    const float* __restrict__ rf, const float* __restrict__ g,
    const float* __restrict__ pr, const float* __restrict__ p,
    float* __restrict__ dst)    // ATOMIC ? out : partials in ws
{
    __shared__ float4 sbuf[2][SLICE_F4];   // 2 x 32 KiB double buffer

    const int bid   = blockIdx.x;
    const int chunk = bid & (N_CHUNKS - 1);          // bid%8 == XCD id: chunk
    const int tile  = (bid >> 3) & (N_TILES - 1);    // pinned per XCD -> rf
    const int b     = bid >> 7;                      // footprint 1 MB per L2
    const int t     = threadIdx.x;
    const int px0   = tile * PX_PER_BLOCK;

    const float c0v = p[b * 4 + 0];
    const float fsv = p[b * 4 + 1];
    const float t0v = p[b * 4 + 2];
    const float scale = fsv / c0v;            // samples per meter
    const float sb0   = scale * t0v;

    float gx[PX_PER_THREAD], gy[PX_PER_THREAD], gzv[PX_PER_THREAD];
#pragma unroll
    for (int j = 0; j < PX_PER_THREAD; ++j) {
        const int m = px0 + j * THREADS + t;
        const float* gp = g + ((size_t)b * NM + m) * 3;
        gx[j]  = gp[0];
        gy[j]  = gp[1];
        gzv[j] = gp[2];
    }

    float4 acc[PX_PER_THREAD];
#pragma unroll
    for (int j = 0; j < PX_PER_THREAD; ++j) acc[j] = make_float4(0.f, 0.f, 0.f, 0.f);

    const int ch0 = chunk * C_PER_BLOCK;
    const float* slice0 = rf + (size_t)(b * NC + ch0) * NS * NK;

    stage_channel(slice0, &sbuf[0][0], t);

    for (int cc = 0; cc < C_PER_BLOCK; ++cc) {
        // vmcnt(0)+barrier: drains the stage into sbuf[cc&1] and protects
        // sbuf[(cc+1)&1] from overwrite while still being read. The stage was
        // issued a full channel-compute earlier, so the drain is already done.
        __syncthreads();
        if (cc + 1 < C_PER_BLOCK)
            stage_channel(slice0 + (size_t)(cc + 1) * NS * NK,
                          &sbuf[(cc + 1) & 1][0], t);  // in flight during compute

        const float4* lb = &sbuf[cc & 1][0];
        const float* prp = pr + ((size_t)(b * NC + ch0 + cc)) * 3;
        const float prx = prp[0], pry = prp[1], prz = prp[2];

#pragma unroll
        for (int j = 0; j < PX_PER_THREAD; ++j) {
            const float dx = gx[j]  - prx;
            const float dy = gy[j]  - pry;
            const float dz = gzv[j] - prz;
            const float drx = __builtin_amdgcn_sqrtf(fmaf(dx, dx, fmaf(dy, dy, dz * dz)));
            // s = fs*(t0 + gz + drx)/c0, folded: one add + one fma
            float s = fmaf(scale, gzv[j] + drx, sb0);
            s = fminf(fmaxf(s, 0.0f), (float)(NS - 1));   // clamp
            const float fi = fminf(floorf(s), (float)(NS - 2));
            const float w  = s - fi;
            const float wm = 1.0f - w;
            const int i0 = (int)fi;
            const float4 y0 = lb[i0];                     // adjacent 32 B:
            const float4 y1 = lb[i0 + 1];                 // 2x ds_read_b128
            acc[j].x = fmaf(y0.x, wm, fmaf(y1.x, w, acc[j].x));
            acc[j].y = fmaf(y0.y, wm, fmaf(y1.y, w, acc[j].y));
            acc[j].z = fmaf(y0.z, wm, fmaf(y1.z, w, acc[j].z));
            acc[j].w = fmaf(y0.w, wm, fmaf(y1.w, w, acc[j].w));
        }
    }

    if (ATOMIC) {
        float* ob = dst + (size_t)b * NM * NK;
#pragma unroll
        for (int j = 0; j < PX_PER_THREAD; ++j) {
            const int m = px0 + j * THREADS + t;
            float* op = ob + (size_t)m * NK;
            atomicAdd(op + 0, acc[j].x);
            atomicAdd(op + 1, acc[j].y);
            atomicAdd(op + 2, acc[j].z);
            atomicAdd(op + 3, acc[j].w);
        }
    } else {
        // partial[chunk][b][m] as float4 — disjoint per block. NON-TEMPORAL:
        // write-once data must not allocate in L2/LLC (it evicts rf and dirty
        // poison lines; R7's 83 MB rf re-fetch came from exactly this).
        f32x4* pw = (f32x4*)dst + (size_t)(chunk * NBATCH + b) * NM;
#pragma unroll
        for (int j = 0; j < PX_PER_THREAD; ++j) {
            const int m = px0 + j * THREADS + t;
            const f32x4 v = {acc[j].x, acc[j].y, acc[j].z, acc[j].w};
            __builtin_nontemporal_store(v, pw + m);
        }
    }
}

// out[i] = sum over 8 chunk partials; i indexes float4 over [B*NM)
__global__ __launch_bounds__(256) void reduce_kernel(
    const f32x4* __restrict__ part, f32x4* __restrict__ out)
{
    const int i = blockIdx.x * 256 + threadIdx.x;
    const size_t stride = (size_t)NBATCH * NM;
    f32x4 a = __builtin_nontemporal_load(part + i);
#pragma unroll
    for (int c = 1; c < N_CHUNKS; ++c) {
        const f32x4 v = __builtin_nontemporal_load(part + c * stride + i);
        a += v;
    }
    out[i] = a;
}

extern "C" void kernel_launch(void* const* d_in, const int* in_sizes, int n_in,
                              void* d_out, int out_size, void* d_ws, size_t ws_size,
                              hipStream_t stream) {
    (void)in_sizes; (void)n_in;
    const float* rf = (const float*)d_in[0];
    const float* g  = (const float*)d_in[1];
    const float* pr = (const float*)d_in[2];
    const float* p  = (const float*)d_in[3];
    float* out = (float*)d_out;

    if (ws_size >= PART_BYTES) {
        das_kernel<false><<<NBLOCKS, THREADS, 0, stream>>>(rf, g, pr, p, (float*)d_ws);
        reduce_kernel<<<(NBATCH * NM) / 256, 256, 0, stream>>>((const f32x4*)d_ws,
                                                               (f32x4*)out);
    } else {
        (void)hipMemsetAsync(d_out, 0, (size_t)out_size * sizeof(float), stream);
        das_kernel<true><<<NBLOCKS, THREADS, 0, stream>>>(rf, g, pr, p, out);
    }
}

// Round 5
// 86.966 us; speedup vs baseline: 1.7016x; 1.0590x over previous
//
#include <hip/hip_runtime.h>
#include <hip/hip_fp16.h>

// DAS beamforming: out[b,z,x,k] = sum_c lerp(rf[b,c], delay(b,c,z,x))[k]
// Round 10: fp16-in-LDS with ON-THE-FLY conversion (R6's gather win without
// R6's fatal flaw of staging via poisoned ws/HBM).
//  das's ~40 us is dominated by the RANDOM LDS gather: f32 float4 samples put
//  64 lanes on 8 sixteen-byte bank-groups (~8-way conflict, ~25 us).
//  fp16 half4 samples: y0+y1 = 16 contiguous B -> ONE ds_read2_b64 per
//  (px,ch) pair (instr count halves) over 16 bank-groups (~4-way) -> ~7 us.
//  Staging is reg-based from the CLEAN rf input (L2-resident): global f32
//  loads issued BEFORE compute (T14 async split), cvt+ds_write after -> no
//  global_load_lds drain at the barrier. ws is never read.
//  Kept from R9: 256 blocks = 2 batch x 16 tiles x 8 chunks (chunk=bid&7
//  pins chunk<->XCD, rf footprint 1 MB/L2), NT partial stores (write-once
//  data must not allocate in the poison-dirty LLC), reduce kernel.

#define NBATCH 2
#define NC 128
#define NS 2048
#define NK 4
#define NM 65536                              // Nz*Nx pixels per batch

#define THREADS 1024
#define PX_PER_THREAD 4
#define PX_PER_BLOCK (THREADS * PX_PER_THREAD)   // 4096
#define C_PER_BLOCK 16
#define N_CHUNKS (NC / C_PER_BLOCK)           // 8
#define N_TILES (NM / PX_PER_BLOCK)           // 16
#define NBLOCKS (NBATCH * N_TILES * N_CHUNKS) // 256 = 1 block/CU

#define PART_BYTES ((size_t)N_CHUNKS * NBATCH * NM * NK * 4)  // 16.8 MB

typedef float f32x4 __attribute__((ext_vector_type(4)));

// pack 8 f32 -> 8 f16 (one half4 sample pair) for LDS residency
__device__ __forceinline__ uint4 cvt8(float4 a, float4 b) {
    const __half2 h0 = __floats2half2_rn(a.x, a.y);
    const __half2 h1 = __floats2half2_rn(a.z, a.w);
    const __half2 h2 = __floats2half2_rn(b.x, b.y);
    const __half2 h3 = __floats2half2_rn(b.z, b.w);
    return make_uint4(__builtin_bit_cast(unsigned, h0),
                      __builtin_bit_cast(unsigned, h1),
                      __builtin_bit_cast(unsigned, h2),
                      __builtin_bit_cast(unsigned, h3));
}

template <bool ATOMIC>
__global__ __launch_bounds__(THREADS, 4) void das_kernel(
    const float* __restrict__ rf, const float* __restrict__ g,
    const float* __restrict__ pr, const float* __restrict__ p,
    float* __restrict__ dst)    // ATOMIC ? out : partials in ws
{
    __shared__ uint4 sbuf[2][NS / 2];   // 2 x 16 KiB fp16 double buffer

    const int bid   = blockIdx.x;
    const int chunk = bid & (N_CHUNKS - 1);          // bid%8 == XCD id
    const int tile  = (bid >> 3) & (N_TILES - 1);
    const int b     = bid >> 7;
    const int t     = threadIdx.x;
    const int px0   = tile * PX_PER_BLOCK;

    const float c0v = p[b * 4 + 0];
    const float fsv = p[b * 4 + 1];
    const float t0v = p[b * 4 + 2];
    const float scale = fsv / c0v;            // samples per meter
    const float sb0   = scale * t0v;

    float gx[PX_PER_THREAD], gy[PX_PER_THREAD], gzv[PX_PER_THREAD];
#pragma unroll
    for (int j = 0; j < PX_PER_THREAD; ++j) {
        const int m = px0 + j * THREADS + t;
        const float* gp = g + ((size_t)b * NM + m) * 3;
        gx[j]  = gp[0];
        gy[j]  = gp[1];
        gzv[j] = gp[2];
    }

    float4 acc[PX_PER_THREAD];
#pragma unroll
    for (int j = 0; j < PX_PER_THREAD; ++j) acc[j] = make_float4(0.f, 0.f, 0.f, 0.f);

    const int ch0 = chunk * C_PER_BLOCK;
    const float* slice0 = rf + (size_t)(b * NC + ch0) * NS * NK;

    // initial stage: slice 0 -> regs -> fp16 -> buf0 (thread t owns 8 floats)
    {
        const float4* s4 = (const float4*)slice0;
        const float4 a0 = s4[2 * t];
        const float4 a1 = s4[2 * t + 1];
        sbuf[0][t] = cvt8(a0, a1);
    }

    for (int cc = 0; cc < C_PER_BLOCK; ++cc) {
        // barrier publishes buf (cc&1) writes from the previous iteration and
        // guarantees everyone finished reading buf ((cc+1)&1) two iters ago.
        __syncthreads();

        // T14 async split: issue next slice's global loads NOW; the vmcnt
        // drain + cvt + ds_write happen after this iteration's compute.
        float4 a0, a1;
        if (cc + 1 < C_PER_BLOCK) {
            const float4* s4 = (const float4*)(slice0 + (size_t)(cc + 1) * NS * NK);
            a0 = s4[2 * t];
            a1 = s4[2 * t + 1];
        }

        const uint2* lb = (const uint2*)&sbuf[cc & 1][0];   // half4 samples
        const float* prp = pr + ((size_t)(b * NC + ch0 + cc)) * 3;
        const float prx = prp[0], pry = prp[1], prz = prp[2];

#pragma unroll
        for (int j = 0; j < PX_PER_THREAD; ++j) {
            const float dx = gx[j]  - prx;
            const float dy = gy[j]  - pry;
            const float dz = gzv[j] - prz;
            const float drx = __builtin_amdgcn_sqrtf(fmaf(dx, dx, fmaf(dy, dy, dz * dz)));
            float s = fmaf(scale, gzv[j] + drx, sb0);      // fs*(t0+gz+drx)/c0
            s = fminf(fmaxf(s, 0.0f), (float)(NS - 1));    // clamp
            const float fi = fminf(floorf(s), (float)(NS - 2));
            const float w  = s - fi;
            const float wm = 1.0f - w;
            const int i0 = (int)fi;
            const uint2 u0 = lb[i0];          // half4 y0 | contiguous 16 B:
            const uint2 u1 = lb[i0 + 1];      // half4 y1 | one ds_read2_b64
            const float2 y0a = __half22float2(__builtin_bit_cast(__half2, u0.x));
            const float2 y0b = __half22float2(__builtin_bit_cast(__half2, u0.y));
            const float2 y1a = __half22float2(__builtin_bit_cast(__half2, u1.x));
            const float2 y1b = __half22float2(__builtin_bit_cast(__half2, u1.y));
            acc[j].x = fmaf(y0a.x, wm, fmaf(y1a.x, w, acc[j].x));
            acc[j].y = fmaf(y0a.y, wm, fmaf(y1a.y, w, acc[j].y));
            acc[j].z = fmaf(y0b.x, wm, fmaf(y1b.x, w, acc[j].z));
            acc[j].w = fmaf(y0b.y, wm, fmaf(y1b.y, w, acc[j].w));
        }

        // drain the prefetch (s_waitcnt auto-inserted), convert, publish on
        // the NEXT barrier. Writing buf ((cc+1)&1) is safe: all waves passed
        // the barrier above, so nobody still reads it from iteration cc-1.
        if (cc + 1 < C_PER_BLOCK)
            sbuf[(cc + 1) & 1][t] = cvt8(a0, a1);
    }

    if (ATOMIC) {
        float* ob = dst + (size_t)b * NM * NK;
#pragma unroll
        for (int j = 0; j < PX_PER_THREAD; ++j) {
            const int m = px0 + j * THREADS + t;
            float* op = ob + (size_t)m * NK;
            atomicAdd(op + 0, acc[j].x);
            atomicAdd(op + 1, acc[j].y);
            atomicAdd(op + 2, acc[j].z);
            atomicAdd(op + 3, acc[j].w);
        }
    } else {
        // partial[chunk][b][m] — disjoint per block. NON-TEMPORAL: write-once
        // data must not allocate in L2/LLC (evicts rf + dirty poison lines).
        f32x4* pw = (f32x4*)dst + (size_t)(chunk * NBATCH + b) * NM;
#pragma unroll
        for (int j = 0; j < PX_PER_THREAD; ++j) {
            const int m = px0 + j * THREADS + t;
            const f32x4 v = {acc[j].x, acc[j].y, acc[j].z, acc[j].w};
            __builtin_nontemporal_store(v, pw + m);
        }
    }
}

// out[i] = sum over 8 chunk partials; i indexes float4 over [B*NM)
__global__ __launch_bounds__(256) void reduce_kernel(
    const f32x4* __restrict__ part, f32x4* __restrict__ out)
{
    const int i = blockIdx.x * 256 + threadIdx.x;
    const size_t stride = (size_t)NBATCH * NM;
    f32x4 a = __builtin_nontemporal_load(part + i);
#pragma unroll
    for (int c = 1; c < N_CHUNKS; ++c) {
        const f32x4 v = __builtin_nontemporal_load(part + c * stride + i);
        a += v;
    }
    out[i] = a;
}

extern "C" void kernel_launch(void* const* d_in, const int* in_sizes, int n_in,
                              void* d_out, int out_size, void* d_ws, size_t ws_size,
                              hipStream_t stream) {
    (void)in_sizes; (void)n_in;
    const float* rf = (const float*)d_in[0];
    const float* g  = (const float*)d_in[1];
    const float* pr = (const float*)d_in[2];
    const float* p  = (const float*)d_in[3];
    float* out = (float*)d_out;

    if (ws_size >= PART_BYTES) {
        das_kernel<false><<<NBLOCKS, THREADS, 0, stream>>>(rf, g, pr, p, (float*)d_ws);
        reduce_kernel<<<(NBATCH * NM) / 256, 256, 0, stream>>>((const f32x4*)d_ws,
                                                               (f32x4*)out);
    } else {
        (void)hipMemsetAsync(d_out, 0, (size_t)out_size * sizeof(float), stream);
        das_kernel<true><<<NBLOCKS, THREADS, 0, stream>>>(rf, g, pr, p, out);
    }
}